// Round 1
// baseline (483.225 us; speedup 1.0000x reference)
//
#include <hip/hip_runtime.h>
#include <hip/hip_bf16.h>

#define M_TOTAL 65536
#define N_TOTAL 1024
#define K_TOTAL 1024
#define BM 128
#define BN 128
#define BK 32
#define LDK 40              // padded LDS K-stride (bf16 elems): 80B rows -> 2-way max conflicts
#define NT (K_TOTAL / BK)   // 32 K-steps

typedef __attribute__((ext_vector_type(8))) short short8;
typedef __attribute__((ext_vector_type(4))) float f32x4;

__device__ __forceinline__ unsigned int fbits(float f) {
    union { float f; unsigned int u; } c; c.f = f; return c.u;
}

// pack hi16(lo), hi16(hi) -> one dword via v_perm_b32 (exact: inputs are
// integer-valued f32 <= 256 in magnitude, so low 16 bits are zero)
__device__ __forceinline__ unsigned int pkhi(float lo, float hi) {
    return __builtin_amdgcn_perm(fbits(hi), fbits(lo), 0x07060302u);
}

__global__ __launch_bounds__(256, 2)
void qlinear_gemm(const float* __restrict__ X,      // [M,K] x_hat
                  const float* __restrict__ SXp,    // scalar s_x
                  const float* __restrict__ Wq,     // [N,K] w_int8 (fp32 ints)
                  const float* __restrict__ SW,     // [N]   s_w
                  const float* __restrict__ Bq,     // [N]   b_int8 (fp32 ints)
                  float* __restrict__ Out)          // [M,N] a_hat
{
    __shared__ ushort As[2][BM][LDK];
    __shared__ ushort Bs[2][BN][LDK];

    const int tid = threadIdx.x;
    const int ntn = N_TOTAL / BN;                 // 8
    const int bm0 = (blockIdx.x / ntn) * BM;
    const int bn0 = (blockIdx.x % ntn) * BN;

    const float sx = SXp[0];
    const float inv_sx = 1.0f / sx;

    // staging: thread t covers row (t>>1), k-halves of 16 floats
    const int sr = tid >> 1;
    const int sh = (tid & 1) << 4;                // 0 or 16

    const float* xg = X  + (size_t)(bm0 + sr) * K_TOTAL + sh;
    const float* wg = Wq + (size_t)(bn0 + sr) * K_TOTAL + sh;

    // wave/fragment indices
    const int lane = tid & 63;
    const int wid  = tid >> 6;
    const int wm   = (wid >> 1) << 6;             // 0 / 64
    const int wn   = (wid & 1) << 6;              // 0 / 64
    const int fr   = lane & 15;
    const int fg   = lane >> 4;                   // k-group, k0 = fg*8

    f32x4 acc[4][4] = {};
    float4 xr[4], wr[4];

    auto load_regs = [&](int kt) {
        const float4* xp = (const float4*)(xg + kt * BK);
        const float4* wp = (const float4*)(wg + kt * BK);
        xr[0] = xp[0]; xr[1] = xp[1]; xr[2] = xp[2]; xr[3] = xp[3];
        wr[0] = wp[0]; wr[1] = wp[1]; wr[2] = wp[2]; wr[3] = wp[3];
    };

    auto store_lds = [&](int buf) {
        unsigned int ux[8], uw[8];
        #pragma unroll
        for (int q = 0; q < 4; ++q) {
            float4 v = xr[q];
            // x_int = rint(x * 1/s_x)  (rint == round-half-even == jnp.round)
            ux[q*2+0] = pkhi(rintf(v.x * inv_sx), rintf(v.y * inv_sx));
            ux[q*2+1] = pkhi(rintf(v.z * inv_sx), rintf(v.w * inv_sx));
            float4 w = wr[q];
            uw[q*2+0] = pkhi(w.x, w.y);
            uw[q*2+1] = pkhi(w.z, w.w);
        }
        uint4* pa = (uint4*)&As[buf][sr][sh];
        pa[0] = make_uint4(ux[0], ux[1], ux[2], ux[3]);
        pa[1] = make_uint4(ux[4], ux[5], ux[6], ux[7]);
        uint4* pb = (uint4*)&Bs[buf][sr][sh];
        pb[0] = make_uint4(uw[0], uw[1], uw[2], uw[3]);
        pb[1] = make_uint4(uw[4], uw[5], uw[6], uw[7]);
    };

    auto compute = [&](int buf) {
        short8 a[4], b[4];
        #pragma unroll
        for (int i = 0; i < 4; ++i)
            a[i] = *(const short8*)&As[buf][wm + i*16 + fr][fg*8];
        #pragma unroll
        for (int j = 0; j < 4; ++j)
            b[j] = *(const short8*)&Bs[buf][wn + j*16 + fr][fg*8];
        #pragma unroll
        for (int i = 0; i < 4; ++i)
            #pragma unroll
            for (int j = 0; j < 4; ++j)
                acc[i][j] = __builtin_amdgcn_mfma_f32_16x16x32_bf16(
                    a[i], b[j], acc[i][j], 0, 0, 0);
    };

    load_regs(0);
    store_lds(0);
    __syncthreads();

    for (int kt = 0; kt < NT; ++kt) {
        const int buf = kt & 1;
        if (kt + 1 < NT) load_regs(kt + 1);   // issue next-tile HBM loads early
        compute(buf);
        if (kt + 1 < NT) {
            __syncthreads();                  // all waves done reading buf^1 (prev iter)
            store_lds(buf ^ 1);
            __syncthreads();                  // writes visible
        }
    }

    // epilogue: (acc + round(b_int8/s_x)) * (s_w * s_x)
    // C/D layout (verified m89/m91): col = lane&15, row = (lane>>4)*4 + reg
    #pragma unroll
    for (int j = 0; j < 4; ++j) {
        const int col = bn0 + wn + j*16 + fr;
        const float sa  = SW[col] * sx;
        const float b32 = rintf(Bq[col] * inv_sx);
        #pragma unroll
        for (int i = 0; i < 4; ++i) {
            const int row0 = bm0 + wm + i*16 + fg*4;
            #pragma unroll
            for (int r = 0; r < 4; ++r) {
                Out[(size_t)(row0 + r) * N_TOTAL + col] = (acc[i][j][r] + b32) * sa;
            }
        }
    }
}

__global__ void sa_tail(const float* __restrict__ SW, const float* __restrict__ SXp,
                        float* __restrict__ Out)
{
    int o = blockIdx.x * blockDim.x + threadIdx.x;
    if (o < N_TOTAL) Out[(size_t)M_TOTAL * N_TOTAL + o] = SW[o] * SXp[0];
}

extern "C" void kernel_launch(void* const* d_in, const int* in_sizes, int n_in,
                              void* d_out, int out_size, void* d_ws, size_t ws_size,
                              hipStream_t stream)
{
    const float* x  = (const float*)d_in[0];
    const float* sx = (const float*)d_in[1];
    const float* wq = (const float*)d_in[2];
    const float* sw = (const float*)d_in[3];
    const float* bq = (const float*)d_in[4];
    float* out = (float*)d_out;

    dim3 grid((M_TOTAL / BM) * (N_TOTAL / BN));   // 4096 blocks
    qlinear_gemm<<<grid, 256, 0, stream>>>(x, sx, wq, sw, bq, out);
    sa_tail<<<4, 256, 0, stream>>>(sw, sx, out);
}